// Round 4
// baseline (1678.323 us; speedup 1.0000x reference)
//
#include <hip/hip_runtime.h>
#include <math.h>

#define NV 128         // vector length (complex) = 8*8*2
#define NTRI 8256      // lower-tri entries of 128x128
#define KAP 0.276f
#define MAXIT 20
#define TPB 512
#define FAN 33         // padded fan dimension of the partial buffer

__device__ __forceinline__ float2 cadd(float2 a, float2 b){ return make_float2(a.x+b.x, a.y+b.y); }
__device__ __forceinline__ float2 csub(float2 a, float2 b){ return make_float2(a.x-b.x, a.y-b.y); }
__device__ __forceinline__ float2 cmul(float2 a, float2 b){ return make_float2(a.x*b.x - a.y*b.y, a.x*b.y + a.y*b.x); }
__device__ __forceinline__ float2 cmulc(float2 a, float2 b){ // conj(a)*b
  return make_float2(a.x*b.x + a.y*b.y, a.x*b.y - a.y*b.x); }
__device__ __forceinline__ float2 cmac(float2 acc, float2 a, float2 b){ // acc += a*b
  acc.x = fmaf(a.x, b.x, fmaf(-a.y, b.y, acc.x));
  acc.y = fmaf(a.x, b.y, fmaf( a.y, b.x, acc.y));
  return acc; }
__device__ __forceinline__ float2 cmacc(float2 acc, float2 a, float2 b){ // acc += conj(a)*b
  acc.x = fmaf(a.x, b.x, fmaf( a.y, b.y, acc.x));
  acc.y = fmaf(a.x, b.y, fmaf(-a.y, b.x, acc.y));
  return acc; }
__device__ __forceinline__ float2 cdiv(float2 n, float2 d){
  float s = 1.0f / fmaf(d.x, d.x, d.y*d.y);
  return make_float2((n.x*d.x + n.y*d.y)*s, (n.y*d.x - n.x*d.y)*s); }

// Wilson-Dirac hop. EF = coefficient sign of G on the FORWARD hop:
//   D : fwd (I - G), bwd (I + G) -> EF=-1 ; Ddag : EF=+1
template<int EF>
__device__ __forceinline__ void dirac(const float2* __restrict__ U,
                                      const float2* __restrict__ vin,
                                      float2* __restrict__ vout, int t)
{
  if (t < NV) {
    const int s = t & 1, site = t >> 1;
    const int yi = site & 7, xi = site >> 3;
    const int xp = (xi+1)&7, xm = (xi-1)&7, yp = (yi+1)&7, ym = (yi-1)&7;
    float2 acc;
    {
      const int bf = (xp<<4) + (yi<<1);
      float2 fs = vin[bf + s], fo = vin[bf + (s^1)];
      float2 cf = (EF > 0) ? cadd(fs, fo) : csub(fs, fo);
      acc = cmul(U[(xi<<3)+yi], cf);
      const int bb = (xm<<4) + (yi<<1);
      float2 bs = vin[bb + s], bo = vin[bb + (s^1)];
      float2 cb = (EF > 0) ? csub(bs, bo) : cadd(bs, bo);
      acc = cadd(acc, cmulc(U[(xm<<3)+yi], cb));
    }
    {
      const float tg = s ? 1.0f : -1.0f;
      const float gf = (float)EF * tg;
      const int bf = (xi<<4) + (yp<<1);
      float2 fs = vin[bf + s], fo = vin[bf + (s^1)];
      float2 cf = make_float2(fmaf(-gf, fo.y, fs.x), fmaf(gf, fo.x, fs.y));
      acc = cadd(acc, cmul(U[64 + (xi<<3)+yi], cf));
      const float gb = -gf;
      const int bb = (xi<<4) + (ym<<1);
      float2 bs = vin[bb + s], bo = vin[bb + (s^1)];
      float2 cb = make_float2(fmaf(-gb, bo.y, bs.x), fmaf(gb, bo.x, bs.y));
      acc = cadd(acc, cmulc(U[64 + (xi<<3)+ym], cb));
    }
    float2 v0 = vin[t];
    vout[t] = make_float2(fmaf(-KAP, acc.x, v0.x), fmaf(-KAP, acc.y, v0.y));
  }
  __syncthreads();
}

// z = L^H (L v) with register-resident L.
// Thread owns rows [r0, r0+cnt) x cols [cb, cb+4) of L (zero-padded above diag).
// part[] is [128][FAN] float2: pass1 bins (row, strip J); pass2 bins (col, q).
__device__ __forceinline__ void precond(const float2 Lreg[5][4], int r0, int has5,
                                        int S, int q,
                                        const float2* __restrict__ vin,
                                        float2* __restrict__ wvv, float2* __restrict__ vout,
                                        float2* __restrict__ part, int t)
{
  const int cb = S << 2;
  // ---- pass 1: partial_r = sum_m L[r][cb+m] v[cb+m] ----
  {
    float4 v01 = *(const float4*)(vin + cb);
    float4 v23 = *(const float4*)(vin + cb + 2);
    float2 vv0 = make_float2(v01.x, v01.y), vv1 = make_float2(v01.z, v01.w);
    float2 vv2 = make_float2(v23.x, v23.y), vv3 = make_float2(v23.z, v23.w);
    #pragma unroll
    for (int k = 0; k < 5; ++k) {
      float2 acc = cmac(make_float2(0.f,0.f), Lreg[k][0], vv0);
      acc = cmac(acc, Lreg[k][1], vv1);
      acc = cmac(acc, Lreg[k][2], vv2);
      acc = cmac(acc, Lreg[k][3], vv3);
      if (k < 4 || has5) part[(r0+k)*FAN + S] = acc;
    }
  }
  __syncthreads();
  // ---- combine w_r = sum_{J <= r>>2} part[r][J] ----
  if (t < NV) {
    const int r = t, lim = r >> 2;
    float2 acc = make_float2(0.f,0.f);
    if (r < 64) {
      #pragma unroll
      for (int J = 0; J < 16; ++J) { float2 p = part[r*FAN+J]; if (J <= lim) acc = cadd(acc, p); }
    } else {
      #pragma unroll
      for (int J = 0; J < 32; ++J) { float2 p = part[r*FAN+J]; if (J <= lim) acc = cadd(acc, p); }
    }
    wvv[r] = acc;
  }
  __syncthreads();
  // ---- pass 2: partial_{cb+m} = sum_k conj(L[r0+k][cb+m]) w[r0+k] ----
  {
    float2 wk0 = wvv[(r0    ) & 127];
    float2 wk1 = wvv[(r0 + 1) & 127];
    float2 wk2 = wvv[(r0 + 2) & 127];
    float2 wk3 = wvv[(r0 + 3) & 127];
    float2 wk4 = wvv[(r0 + 4) & 127];   // k=4 of cnt-4 threads pairs with Lreg[4]=0
    #pragma unroll
    for (int m = 0; m < 4; ++m) {
      float2 acc = cmacc(make_float2(0.f,0.f), Lreg[0][m], wk0);
      acc = cmacc(acc, Lreg[1][m], wk1);
      acc = cmacc(acc, Lreg[2][m], wk2);
      acc = cmacc(acc, Lreg[3][m], wk3);
      acc = cmacc(acc, Lreg[4][m], wk4);
      part[(cb+m)*FAN + q] = acc;
    }
  }
  __syncthreads();
  // ---- combine z_j = sum_{q < fan(S_j)} part[j][q] ----
  if (t < NV) {
    const int j = t, Sj = j >> 2;
    const int qmax = (j < 64) ? (30 - Sj) : (31 - Sj);  // fan = 31-S (A) or 32-S (B)
    float2 acc = make_float2(0.f,0.f);
    if (j < 64) {
      #pragma unroll
      for (int Q = 0; Q < 31; ++Q) { float2 p = part[j*FAN+Q]; if (Q <= qmax) acc = cadd(acc, p); }
    } else {
      #pragma unroll
      for (int Q = 0; Q < 16; ++Q) { float2 p = part[j*FAN+Q]; if (Q <= qmax) acc = cadd(acc, p); }
    }
    vout[j] = acc;
  }
  // no trailing barrier: vout[j] is re-read only by thread j before the next barrier,
  // and part[] is not rewritten before >=1 barrier downstream.
}

// conj(a).c over t<128; scal slot double-buffered, internal barrier publishes.
__device__ __forceinline__ float2 block_dot(const float2* __restrict__ a, const float2* __restrict__ c,
                            float2* __restrict__ scal, int t, int slot)
{
  if (t < NV) {
    float2 v = cmacc(make_float2(0.f,0.f), a[t], c[t]);
    #pragma unroll
    for (int off = 32; off > 0; off >>= 1) {
      v.x += __shfl_down(v.x, off, 64);
      v.y += __shfl_down(v.y, off, 64);
    }
    if ((t & 63) == 0) scal[(slot<<1) + (t >> 6)] = v;
  }
  __syncthreads();
  return cadd(scal[slot<<1], scal[(slot<<1)+1]);
}

extern "C" __global__ void __launch_bounds__(TPB, 6)
cg_loss_kernel(const float* __restrict__ nre, const float* __restrict__ nim,
               const float* __restrict__ theta, const float* __restrict__ bin,
               float* __restrict__ out, float invB)
{
  __shared__ __align__(16) float2 part[128*FAN];   // 33792 B
  __shared__ __align__(16) float2 Uc[128];
  __shared__ __align__(16) float2 bv[NV], xv[NV], rv[NV], pv[NV];
  __shared__ __align__(16) float2 zv[NV], Apv[NV], tv[NV], wv[NV];
  __shared__ float2 scal[8];
  // total LDS = 33792 + 1024 + 8*1024 + 64 = 43072 B -> 3 blocks/CU

  const int t = threadIdx.x;
  const long long b = blockIdx.x;

  // ---- thread -> (strip S, within-strip ordinal q, rows [r0, r0+cnt)) ----
  const int P = t >> 5, u = t & 31;
  const int nA = 31 - P;
  int S, q, r0, has5;
  if (u < nA) { S = P;      q = u;      has5 = (u < 4); r0 = (P<<2) + (has5 ? 5*u : 4*u + 4); }
  else        { S = 31 - P; q = u - nA; has5 = 0;       r0 = (S<<2) + (q<<2); }
  const int cb = S << 2;
  const int cnt = has5 ? 5 : 4;

  // ---- stage L directly into registers (each entry read exactly once grid-wide) ----
  float2 Lreg[5][4];
  {
    const float* nreb = nre + b * NTRI;
    const float* nimb = nim + b * NTRI;
    #pragma unroll
    for (int k = 0; k < 5; ++k) {
      const int r = r0 + k;
      const int base = (r*(r+1)) >> 1;
      #pragma unroll
      for (int m = 0; m < 4; ++m) {
        const int c = cb + m;
        const bool val = (k < cnt) && (c <= r);
        float re = val ? nreb[base + c] : 0.f;
        float im = val ? nimb[base + c] : 0.f;
        Lreg[k][m] = make_float2(re, im);
      }
    }
  }
  if (t < NV) {
    float th = theta[b * 128 + t];
    float sn, cs;
    sincosf(th, &sn, &cs);
    Uc[t] = make_float2(cs, sn);                    // exp(i*theta)
    float bb = bin[b * 128 + t];
    bv[t] = make_float2(bb, 0.f);
    xv[t] = make_float2(0.f, 0.f);
    rv[t] = make_float2(bb, 0.f);                   // r = b - A(0)
  }
  __syncthreads();

  precond(Lreg, r0, has5, S, q, rv, wv, zv, part, t);   // z = M r
  if (t < NV) pv[t] = zv[t];
  float2 rz = block_dot(rv, zv, scal, t, 0);            // internal barrier publishes pv

  #pragma unroll 1
  for (int it = 0; it < MAXIT; ++it) {
    dirac<-1>(Uc, pv, tv, t);                       // t1 = D p
    dirac<+1>(Uc, tv, Apv, t);                      // Ap = Ddag t1
    float2 pAp = block_dot(pv, Apv, scal, t, 1);
    if (t < NV) {
      float2 alpha = cdiv(rz, pAp);
      xv[t] = cmac(xv[t], alpha, pv[t]);            // x += alpha p
      rv[t] = csub(rv[t], cmul(alpha, Apv[t]));     // r -= alpha Ap
    }
    __syncthreads();                                // rv visible to pass 1
    precond(Lreg, r0, has5, S, q, rv, wv, zv, part, t); // z = M r
    float2 rz2 = block_dot(rv, zv, scal, t, 0);
    if (t < NV) {
      float2 beta = cdiv(rz2, rz);
      pv[t] = cmac(zv[t], beta, pv[t]);             // p = z + beta p
    }
    rz = rz2;
    __syncthreads();                                // pv visible to next dirac
  }

  // res = A x - b ; rn = ||res||
  dirac<-1>(Uc, xv, tv, t);
  dirac<+1>(Uc, tv, Apv, t);
  if (t < NV) {
    float2 d = csub(Apv[t], bv[t]);
    float v = fmaf(d.x, d.x, d.y * d.y);
    #pragma unroll
    for (int off = 32; off > 0; off >>= 1) v += __shfl_down(v, off, 64);
    if ((t & 63) == 0) scal[4 + (t >> 6)].x = v;
  }
  __syncthreads();
  if (t == 0) {
    float rn = sqrtf(scal[4].x + scal[5].x);
    atomicAdd(out, rn * invB);
  }
}

extern "C" void kernel_launch(void* const* d_in, const int* in_sizes, int n_in,
                              void* d_out, int out_size, void* d_ws, size_t ws_size,
                              hipStream_t stream)
{
  const float* nre   = (const float*)d_in[0];
  const float* nim   = (const float*)d_in[1];
  const float* theta = (const float*)d_in[2];
  const float* bin   = (const float*)d_in[3];
  float* out = (float*)d_out;
  const int B = in_sizes[0] / NTRI;   // 2048

  hipMemsetAsync(out, 0, sizeof(float), stream);
  cg_loss_kernel<<<B, TPB, 0, stream>>>(nre, nim, theta, bin, out, 1.0f / (float)B);
}

// Round 5
// 514.296 us; speedup vs baseline: 3.2633x; 3.2633x over previous
//
#include <hip/hip_runtime.h>
#include <math.h>

#define NV 128         // vector length (complex) = 8*8*2
#define NTRI 8256      // lower-tri entries of 128x128
#define NPAD 8320      // row-padded triangle (each row even length)
#define KAP 0.276f
#define MAXIT 20
#define TPB 512        // 8 waves; LDS ~76 KB -> 2 blocks/CU

__device__ __forceinline__ float2 f2(float x, float y){ return make_float2(x, y); }
__device__ __forceinline__ float2 cadd(float2 a, float2 b){ return make_float2(a.x+b.x, a.y+b.y); }
__device__ __forceinline__ float2 csub(float2 a, float2 b){ return make_float2(a.x-b.x, a.y-b.y); }
__device__ __forceinline__ float2 cmul(float2 a, float2 b){ return make_float2(a.x*b.x - a.y*b.y, a.x*b.y + a.y*b.x); }
__device__ __forceinline__ float2 cmulc(float2 a, float2 b){ // conj(a)*b
  return make_float2(a.x*b.x + a.y*b.y, a.x*b.y - a.y*b.x); }
__device__ __forceinline__ float2 cmac(float2 acc, float2 a, float2 b){ // acc += a*b
  acc.x = fmaf(a.x, b.x, fmaf(-a.y, b.y, acc.x));
  acc.y = fmaf(a.x, b.y, fmaf( a.y, b.x, acc.y));
  return acc; }
__device__ __forceinline__ float2 cmacc(float2 acc, float2 a, float2 b){ // acc += conj(a)*b
  acc.x = fmaf(a.x, b.x, fmaf( a.y, b.y, acc.x));
  acc.y = fmaf(a.x, b.y, fmaf(-a.y, b.x, acc.y));
  return acc; }
__device__ __forceinline__ float2 cdiv(float2 n, float2 d){
  float s = 1.0f / fmaf(d.x, d.x, d.y*d.y);
  return make_float2((n.x*d.x + n.y*d.y)*s, (n.y*d.x - n.x*d.y)*s); }

// rowOff(r) = tri(r) + ceil(r/2): start of row r in the padded triangle; always even.
__device__ __forceinline__ int rowoff(int r){ return ((r*(r+1)) >> 1) + ((r+1) >> 1); }

// Wilson-Dirac hop. EF = coefficient sign of G on the FORWARD hop:
//   D : fwd (I - G), bwd (I + G) -> EF=-1 ; Ddag : EF=+1
template<int EF>
__device__ __forceinline__ void dirac(const float2* __restrict__ U,
                                      const float2* __restrict__ vin,
                                      float2* __restrict__ vout, int t)
{
  if (t < NV) {
    const int s = t & 1, site = t >> 1;
    const int yi = site & 7, xi = site >> 3;
    const int xp = (xi+1)&7, xm = (xi-1)&7, yp = (yi+1)&7, ym = (yi-1)&7;
    float2 acc;
    {
      const int bf = (xp<<4) + (yi<<1);
      float2 fs = vin[bf + s], fo = vin[bf + (s^1)];
      float2 cf = (EF > 0) ? cadd(fs, fo) : csub(fs, fo);
      acc = cmul(U[(xi<<3)+yi], cf);
      const int bb = (xm<<4) + (yi<<1);
      float2 bs = vin[bb + s], bo = vin[bb + (s^1)];
      float2 cb = (EF > 0) ? csub(bs, bo) : cadd(bs, bo);
      acc = cadd(acc, cmulc(U[(xm<<3)+yi], cb));
    }
    {
      const float tg = s ? 1.0f : -1.0f;
      const float gf = (float)EF * tg;
      const int bf = (xi<<4) + (yp<<1);
      float2 fs = vin[bf + s], fo = vin[bf + (s^1)];
      float2 cf = make_float2(fmaf(-gf, fo.y, fs.x), fmaf(gf, fo.x, fs.y));
      acc = cadd(acc, cmul(U[64 + (xi<<3)+yi], cf));
      const float gb = -gf;
      const int bb = (xi<<4) + (ym<<1);
      float2 bs = vin[bb + s], bo = vin[bb + (s^1)];
      float2 cb = make_float2(fmaf(-gb, bo.y, bs.x), fmaf(gb, bo.x, bs.y));
      acc = cadd(acc, cmulc(U[64 + (xi<<3)+ym], cb));
    }
    float2 v0 = vin[t];
    vout[t] = make_float2(fmaf(-KAP, acc.x, v0.x), fmaf(-KAP, acc.y, v0.y));
  }
  __syncthreads();
}

// z = L^H (L v), L in row-padded LDS.
// Wave w (0..7): pass 1 rows 16w+g, pass 2 cols 16w+g (g = lane>>2);
// the 4 lanes c = lane&3 of each row/col split the 8-wide k-slabs and
// combine via 2 shfl_xor steps. No part[] buffer, 3 barriers total.
__device__ __forceinline__ void precond(const float2* __restrict__ Lc2,
                                        const float2* __restrict__ vin,
                                        float2* __restrict__ wvv,
                                        float2* __restrict__ vout,
                                        int w, int g, int c)
{
  // ---- pass 1: w_r = sum_{j<=r} L[r][j] v[j] ----
  {
    const int r = (w << 4) + g;
    const int bR = rowoff(r);
    float2 acc = f2(0.f, 0.f);
    const int kc = w << 1;                    // clean iterations: k = 0 .. 2w-1
    for (int k = 0; k < kc; ++k) {
      const int j0 = (k << 3) + (c << 1);
      float4 Lp = *(const float4*)&Lc2[bR + j0];
      float4 vp = *(const float4*)&vin[j0];
      acc = cmac(acc, f2(Lp.x, Lp.y), f2(vp.x, vp.y));
      acc = cmac(acc, f2(Lp.z, Lp.w), f2(vp.z, vp.w));
    }
    #pragma unroll
    for (int pk = 0; pk < 2; ++pk) {          // peeled k = 2w, 2w+1 (diagonal slab)
      const int j0 = ((kc + pk) << 3) + (c << 1);
      float4 Lp = *(const float4*)&Lc2[bR + j0];
      float4 vp = *(const float4*)&vin[j0];
      float2 La = (j0     <= r) ? f2(Lp.x, Lp.y) : f2(0.f, 0.f);
      float2 Lb = (j0 + 1 <= r) ? f2(Lp.z, Lp.w) : f2(0.f, 0.f);
      acc = cmac(acc, La, f2(vp.x, vp.y));
      acc = cmac(acc, Lb, f2(vp.z, vp.w));
    }
    acc.x += __shfl_xor(acc.x, 1); acc.y += __shfl_xor(acc.y, 1);
    acc.x += __shfl_xor(acc.x, 2); acc.y += __shfl_xor(acc.y, 2);
    if (c == 0) wvv[r] = acc;
  }
  __syncthreads();
  // ---- pass 2: z_j = sum_{i>=j} conj(L[i][j]) w[i] ----
  {
    const int j = (w << 4) + g;
    float2 acc = f2(0.f, 0.f);
    const int kc = (w << 1) + 2;
    #pragma unroll
    for (int pk = 0; pk < 2; ++pk) {          // peeled k = 2w, 2w+1 (diagonal slab)
      const int i0 = ((2*w + pk) << 3) + (c << 1);
      float2 La = Lc2[rowoff(i0)     + j];
      float2 Lb = Lc2[rowoff(i0 + 1) + j];
      float4 wp = *(const float4*)&wvv[i0];
      if (i0     < j) La = f2(0.f, 0.f);
      if (i0 + 1 < j) Lb = f2(0.f, 0.f);
      acc = cmacc(acc, La, f2(wp.x, wp.y));
      acc = cmacc(acc, Lb, f2(wp.z, wp.w));
    }
    for (int k = kc; k < 16; ++k) {           // clean: i >= 16w+16 > j always
      const int i0 = (k << 3) + (c << 1);
      float2 La = Lc2[rowoff(i0)     + j];
      float2 Lb = Lc2[rowoff(i0 + 1) + j];
      float4 wp = *(const float4*)&wvv[i0];
      acc = cmacc(acc, La, f2(wp.x, wp.y));
      acc = cmacc(acc, Lb, f2(wp.z, wp.w));
    }
    acc.x += __shfl_xor(acc.x, 1); acc.y += __shfl_xor(acc.y, 1);
    acc.x += __shfl_xor(acc.x, 2); acc.y += __shfl_xor(acc.y, 2);
    if (c == 0) vout[j] = acc;
  }
  __syncthreads();                            // z visible to all consumers
}

// conj(a).c over t<128; scal slot double-buffered; internal barrier.
__device__ __forceinline__ float2 block_dot(const float2* __restrict__ a, const float2* __restrict__ c,
                            float2* __restrict__ scal, int t, int slot)
{
  if (t < NV) {
    float2 v = cmacc(f2(0.f,0.f), a[t], c[t]);
    #pragma unroll
    for (int off = 32; off > 0; off >>= 1) {
      v.x += __shfl_down(v.x, off, 64);
      v.y += __shfl_down(v.y, off, 64);
    }
    if ((t & 63) == 0) scal[(slot<<1) + (t >> 6)] = v;
  }
  __syncthreads();
  return cadd(scal[slot<<1], scal[(slot<<1)+1]);
}

extern "C" __global__ void __launch_bounds__(TPB, 4)
cg_loss_kernel(const float* __restrict__ nre, const float* __restrict__ nim,
               const float* __restrict__ theta, const float* __restrict__ bin,
               float* __restrict__ out, float invB)
{
  __shared__ __align__(16) float2 Lc2[NPAD];        // 66560 B row-padded triangle
  __shared__ __align__(16) float2 Uc[128];
  __shared__ __align__(16) float2 bv[NV], xv[NV], rv[NV], pv[NV];
  __shared__ __align__(16) float2 zv[NV], Apv[NV], tv[NV], wv[NV];
  __shared__ float2 scal[8];
  // total LDS = 66560 + 1024 + 8192 + 64 = 75840 B -> 2 blocks/CU

  const int t = threadIdx.x;
  const long long b = blockIdx.x;
  const int w = t >> 6, lane = t & 63, g = lane >> 2, c = lane & 3;

  // ---- stage L into padded LDS; global reads fully coalesced (b32 strided) ----
  {
    const float* nreb = nre + b * NTRI;
    const float* nimb = nim + b * NTRI;
    for (int p = t; p < NTRI; p += TPB) {
      float re = nreb[p], im = nimb[p];
      int r = (int)((sqrtf(8.f * (float)p + 1.f) - 1.f) * 0.5f + 1e-3f);
      int tr = (r * (r + 1)) >> 1;
      if (tr > p)               { tr -= r; --r; }        // tri(r-1) = tri(r) - r
      else if (tr + r + 1 <= p) { tr += r + 1; ++r; }
      const int jj = p - tr;
      Lc2[tr + ((r + 1) >> 1) + jj] = make_float2(re, im);
    }
  }
  if (t < NV) {
    float th = theta[b * 128 + t];
    float sn, cs;
    sincosf(th, &sn, &cs);
    Uc[t] = make_float2(cs, sn);                    // exp(i*theta)
    float bb = bin[b * 128 + t];
    bv[t] = make_float2(bb, 0.f);
    xv[t] = make_float2(0.f, 0.f);
    rv[t] = make_float2(bb, 0.f);                   // r = b - A(0)
  }
  __syncthreads();

  precond(Lc2, rv, wv, zv, w, g, c);                // z = M r
  if (t < NV) pv[t] = zv[t];
  float2 rz = block_dot(rv, zv, scal, t, 0);        // internal barrier publishes pv

  #pragma unroll 1
  for (int it = 0; it < MAXIT; ++it) {
    dirac<-1>(Uc, pv, tv, t);                       // t1 = D p
    dirac<+1>(Uc, tv, Apv, t);                      // Ap = Ddag t1
    float2 pAp = block_dot(pv, Apv, scal, t, 1);
    if (t < NV) {
      float2 alpha = cdiv(rz, pAp);
      xv[t] = cmac(xv[t], alpha, pv[t]);            // x += alpha p
      rv[t] = csub(rv[t], cmul(alpha, Apv[t]));     // r -= alpha Ap
    }
    __syncthreads();                                // rv visible to pass 1
    precond(Lc2, rv, wv, zv, w, g, c);              // z = M r
    float2 rz2 = block_dot(rv, zv, scal, t, 0);
    if (t < NV) {
      float2 beta = cdiv(rz2, rz);
      pv[t] = cmac(zv[t], beta, pv[t]);             // p = z + beta p
    }
    rz = rz2;
    __syncthreads();                                // pv visible to next dirac
  }

  // res = A x - b ; rn = ||res||
  dirac<-1>(Uc, xv, tv, t);
  dirac<+1>(Uc, tv, Apv, t);
  if (t < NV) {
    float2 d = csub(Apv[t], bv[t]);
    float v = fmaf(d.x, d.x, d.y * d.y);
    #pragma unroll
    for (int off = 32; off > 0; off >>= 1) v += __shfl_down(v, off, 64);
    if ((t & 63) == 0) scal[4 + (t >> 6)].x = v;
  }
  __syncthreads();
  if (t == 0) {
    float rn = sqrtf(scal[4].x + scal[5].x);
    atomicAdd(out, rn * invB);
  }
}

extern "C" void kernel_launch(void* const* d_in, const int* in_sizes, int n_in,
                              void* d_out, int out_size, void* d_ws, size_t ws_size,
                              hipStream_t stream)
{
  const float* nre   = (const float*)d_in[0];
  const float* nim   = (const float*)d_in[1];
  const float* theta = (const float*)d_in[2];
  const float* bin   = (const float*)d_in[3];
  float* out = (float*)d_out;
  const int B = in_sizes[0] / NTRI;   // 2048

  hipMemsetAsync(out, 0, sizeof(float), stream);
  cg_loss_kernel<<<B, TPB, 0, stream>>>(nre, nim, theta, bin, out, 1.0f / (float)B);
}